// Round 4
// baseline (277.629 us; speedup 1.0000x reference)
//
#include <hip/hip_runtime.h>
#include <hip/hip_bf16.h>
#include <hip/hip_cooperative_groups.h>

namespace cg = cooperative_groups;

// B=8, C=192, N=3136, K=9, COUT=384.
// out[b,o,n] = relu( bias[o] + max_k( u[b,i1,o] + v[b,i0,o] ) )
//   u = (W1-W2)·xs,  v = W2·xs
// SINGLE fused cooperative kernel, 3 grid-stride phases with grid.sync() between:
//   A: dtype-detect (per block) + x->xT[b][n][200] bf16 + W->A_Tb[j][200] bf16
//   B: GEMM T[b][n][768], 64x64 tiles, single-shot K=192, linear global_load_lds
//      staging (global tile is byte-image of LDS tile), conflict-optimal 400B rows
//   C: gather+max+bias+relu; thirds of 128 ch (1.6MB/(b,third) < 4MB XCD L2),
//      per-XCD batch affinity (b = bid&7), byte-offsets staged in LDS, 16B loads
// Fusion removes 2 launches + 2 full-grid drains and makes the whole pipeline ONE
// dispatch (> fill time) so rocprof top-5 finally attributes counters to our code.
// ws: (flags unused) | A_Tb @1KB | x_T @512KB | T @11MB   ~= 49.5MB

#define Bb   8
#define Cc   192
#define Nn   3136
#define Kk   9
#define CO   384
#define TWOC 384
#define JTOT 768
#define PADC 200   // row length in xT/A_Tb AND LDS (shorts): 400B rows

typedef short  short8 __attribute__((ext_vector_type(8)));
typedef float  f32x4  __attribute__((ext_vector_type(4)));

__device__ __forceinline__ float bf2f(unsigned int u16) {
    union { unsigned int i; float f; } c;
    c.i = u16 << 16;
    return c.f;
}
__device__ __forceinline__ float bflo(unsigned int u) {
    union { unsigned int i; float f; } c;
    c.i = u << 16;
    return c.f;
}
__device__ __forceinline__ float bfhi(unsigned int u) {
    union { unsigned int i; float f; } c;
    c.i = u & 0xffff0000u;
    return c.f;
}
__device__ __forceinline__ short f2bf(float f) {
    __hip_bfloat16 h = __float2bfloat16(f);
    short s; __builtin_memcpy(&s, &h, 2); return s;
}
__device__ __forceinline__ void gload16(const void* g, void* l) {
    __builtin_amdgcn_global_load_lds(
        (const __attribute__((address_space(1))) unsigned int*)g,
        (__attribute__((address_space(3))) unsigned int*)l, 16, 0, 0);
}

__global__ __launch_bounds__(256, 3) void fused_all(
    const void* __restrict__ x_, const int* __restrict__ ei,
    const void* __restrict__ W_, const void* __restrict__ bias_,
    void* __restrict__ out_, short* __restrict__ xT,
    short* __restrict__ A_Tb, short* __restrict__ T)
{
    cg::grid_group grid = cg::this_grid();
    __shared__ char smem[51200];           // phase B: Asl(25600)+Bsl(25600)
    __shared__ int sflag, sis64;
    const int tid = threadIdx.x;
    const int bid = blockIdx.x;
    const int nblk = gridDim.x;            // multiple of 8

    // per-block dtype detect
    if (tid < 64) {
        unsigned int u = ((const unsigned short*)x_)[2 * tid];
        int bige = (((u >> 7) & 0xFFu) >= 0x88u);   // impossible for N(0,1) bf16
        unsigned long long bf = __ballot(bige);
        if (tid == 0) sflag = (bf != 0ull) ? 1 : 0;
        int oddnz = (ei[2 * tid + 1] != 0);
        unsigned long long bo = __ballot(oddnz);
        if (tid == 0) sis64 = (bo == 0ull) ? 1 : 0;
    }
    __syncthreads();
    const int fp32 = sflag;
    const int is64 = sis64;

    // ================= Phase A: transpose x + prep W =================
    {
        float (*s)[33] = (float (*)[33])smem;       // 8448 B
        for (int u = bid; u < 2928; u += nblk) {
            if (u < 2352) {
                int b   = u / 294;                  // 294 = 6*49
                int rem = u - b * 294;
                int ct  = rem / 49;
                int nt  = rem - ct * 49;
                const int n0 = nt * 64;
                const int c0 = ct * 32;
                const int cl   = tid >> 3;
                const int nseg = tid & 7;

                if (fp32) {
                    const float* p = (const float*)x_ + ((size_t)b * Cc + c0 + cl) * Nn + n0 + nseg * 8;
                    float4 v0 = *(const float4*)p;
                    float4 v1 = *(const float4*)(p + 4);
                    int nb = nseg * 8;
                    s[nb + 0][cl] = v0.x;  s[nb + 1][cl] = v0.y;
                    s[nb + 2][cl] = v0.z;  s[nb + 3][cl] = v0.w;
                    s[nb + 4][cl] = v1.x;  s[nb + 5][cl] = v1.y;
                    s[nb + 6][cl] = v1.z;  s[nb + 7][cl] = v1.w;
                } else {
                    const unsigned short* p = (const unsigned short*)x_ + ((size_t)b * Cc + c0 + cl) * Nn + n0 + nseg * 8;
                    ushort4 u0 = *(const ushort4*)p;
                    ushort4 u1 = *(const ushort4*)(p + 4);
                    int nb = nseg * 8;
                    s[nb + 0][cl] = bf2f(u0.x);  s[nb + 1][cl] = bf2f(u0.y);
                    s[nb + 2][cl] = bf2f(u0.z);  s[nb + 3][cl] = bf2f(u0.w);
                    s[nb + 4][cl] = bf2f(u1.x);  s[nb + 5][cl] = bf2f(u1.y);
                    s[nb + 6][cl] = bf2f(u1.z);  s[nb + 7][cl] = bf2f(u1.w);
                }
                __syncthreads();

                const int nl = tid >> 2;
                const int cs = tid & 3;
                short8 o;
#pragma unroll
                for (int i = 0; i < 8; ++i) o[i] = f2bf(s[nl][cs * 8 + i]);
                *(short8*)(xT + ((size_t)b * Nn + n0 + nl) * PADC + c0 + cs * 8) = o;
            } else {
                int t = (u - 2352) * 256 + tid;     // 0..147455
                int j = t / Cc;
                int c = t - j * Cc;
                int row = (j < CO) ? j : (j - CO);
                float w1, w2;
                if (fp32) {
                    const float* W = (const float*)W_;
                    w1 = W[row * TWOC + c];  w2 = W[row * TWOC + Cc + c];
                } else {
                    const unsigned short* W = (const unsigned short*)W_;
                    w1 = bf2f(W[row * TWOC + c]);  w2 = bf2f(W[row * TWOC + Cc + c]);
                }
                A_Tb[(size_t)j * PADC + c] = f2bf((j < CO) ? (w1 - w2) : w2);
            }
            __syncthreads();   // protect s reuse across iterations (branch is block-uniform)
        }
    }
    __threadfence();
    grid.sync();

    // ================= Phase B: MFMA GEMM =================
    {
        short* Asl = (short*)smem;             // 25600 B [n][c]
        short* Bsl = (short*)(smem + 25600);   // 25600 B [j][c]
        const int w    = tid >> 6;
        const int lane = tid & 63;
        const int col  = lane & 15;
        const int quad = lane >> 4;

        for (int t = bid; t < 4704; t += nblk) {
            const int jt   = t % 12;
            const int rest = t / 12;
            const int b    = rest & 7;
            const int nt   = rest >> 3;
            const int n0 = nt * 64, j0 = jt * 64;

            const short* gA = xT   + ((size_t)b * Nn + n0) * PADC;
            const short* gB = A_Tb + (size_t)j0 * PADC;
            for (int c = w; c < 25; c += 4) {
                gload16(gA + c * 512 + lane * 8, Asl + c * 512);
                gload16(gB + c * 512 + lane * 8, Bsl + c * 512);
            }
            __syncthreads();

            f32x4 acc[4];
#pragma unroll
            for (int i = 0; i < 4; ++i) acc[i] = (f32x4)(0.0f);

#pragma unroll
            for (int kf = 0; kf < 6; ++kf) {
                short8 bfr = *(const short8*)(Bsl + (w * 16 + col) * PADC + kf * 32 + quad * 8);
#pragma unroll
                for (int fm = 0; fm < 4; ++fm) {
                    short8 a = *(const short8*)(Asl + (fm * 16 + col) * PADC + kf * 32 + quad * 8);
                    acc[fm] = __builtin_amdgcn_mfma_f32_16x16x32_bf16(a, bfr, acc[fm], 0, 0, 0);
                }
            }
            __syncthreads();   // LDS reads done; reuse Asl as C-tile

            short* Ct = Asl;
#pragma unroll
            for (int fm = 0; fm < 4; ++fm) {
#pragma unroll
                for (int r = 0; r < 4; ++r) {
                    Ct[(fm * 16 + quad * 4 + r) * 72 + w * 16 + col] = f2bf(acc[fm][r]);
                }
            }
            __syncthreads();

            {
                const int row = tid >> 2;
                const int gq  = tid & 3;
#pragma unroll
                for (int i = 0; i < 2; ++i) {
                    int g = gq + i * 4;
                    *(short8*)(T + ((size_t)(b * Nn + n0 + row)) * JTOT + j0 + g * 8) =
                        *(const short8*)(Ct + row * 72 + g * 8);
                }
            }
            __syncthreads();   // before next-iter staging overwrites Asl/Bsl
        }
    }
    __threadfence();
    grid.sync();

    // ================= Phase C: gather + max + bias + relu =================
    // thirds of 128 channels; per-XCD batch affinity: b = bid&7.
    {
        float (*sm)[129]  = (float (*)[129])smem;          // 16512 B (129 pad: conflict-free col reads)
        int (*soff0)[Kk]  = (int (*)[Kk])(smem + 16512);   // 1152 B
        int (*soff1)[Kk]  = (int (*)[Kk])(smem + 17664);   // 1152 B
        const int b   = bid & 7;
        const int pb  = nblk >> 3;          // blocks per batch
        const char* Tb = (const char*)T + (size_t)b * Nn * JTOT * 2;
        const int cgi = tid & 7;
        const int seg = tid >> 3;

        for (int s = (bid >> 3); s < 294; s += pb) {
            const int third = s / 98;
            const int nt    = s - third * 98;
            const int n0    = nt * 32;

            for (int q = tid; q < 32 * 2 * Kk; q += 256) {
                int ln = q / (2 * Kk);
                int slot = q - ln * (2 * Kk);
                int n = n0 + ln;
                size_t pos; int* dstp;
                if (slot < Kk) { pos = ((size_t)b * Nn + n) * Kk + slot;               dstp = &soff0[ln][slot]; }
                else           { pos = ((size_t)(Bb + b) * Nn + n) * Kk + (slot - Kk); dstp = &soff1[ln][slot - Kk]; }
                int v = is64 ? ei[2 * pos] : ei[pos];
                v = (v < 0) ? 0 : (v >= Nn ? Nn - 1 : v);
                *dstp = v * (JTOT * 2);
            }
            __syncthreads();

            const int och = third * 128 + cgi * 16;
            const char* Tu = Tb + (size_t)och * 2;
            const char* Tv = Tb + (size_t)(CO + och) * 2;

            float bv[16];
            if (fp32) {
                const float* bp = (const float*)bias_ + och;
#pragma unroll
                for (int j = 0; j < 16; ++j) bv[j] = bp[j];
            } else {
                const unsigned short* bp = (const unsigned short*)bias_ + och;
#pragma unroll
                for (int j = 0; j < 16; ++j) bv[j] = bf2f(bp[j]);
            }

            float mm[16];
#pragma unroll
            for (int j = 0; j < 16; ++j) mm[j] = -INFINITY;

#pragma unroll
            for (int k = 0; k < Kk; ++k) {
                const int o1 = soff1[seg][k];
                const int o0 = soff0[seg][k];
                uint4 ua = *(const uint4*)(Tu + o1);
                uint4 ub = *(const uint4*)(Tu + o1 + 16);
                uint4 va = *(const uint4*)(Tv + o0);
                uint4 vb = *(const uint4*)(Tv + o0 + 16);
                mm[0]  = fmaxf(mm[0],  bflo(ua.x) + bflo(va.x));
                mm[1]  = fmaxf(mm[1],  bfhi(ua.x) + bfhi(va.x));
                mm[2]  = fmaxf(mm[2],  bflo(ua.y) + bflo(va.y));
                mm[3]  = fmaxf(mm[3],  bfhi(ua.y) + bfhi(va.y));
                mm[4]  = fmaxf(mm[4],  bflo(ua.z) + bflo(va.z));
                mm[5]  = fmaxf(mm[5],  bfhi(ua.z) + bfhi(va.z));
                mm[6]  = fmaxf(mm[6],  bflo(ua.w) + bflo(va.w));
                mm[7]  = fmaxf(mm[7],  bfhi(ua.w) + bfhi(va.w));
                mm[8]  = fmaxf(mm[8],  bflo(ub.x) + bflo(vb.x));
                mm[9]  = fmaxf(mm[9],  bfhi(ub.x) + bfhi(vb.x));
                mm[10] = fmaxf(mm[10], bflo(ub.y) + bflo(vb.y));
                mm[11] = fmaxf(mm[11], bfhi(ub.y) + bfhi(vb.y));
                mm[12] = fmaxf(mm[12], bflo(ub.z) + bflo(vb.z));
                mm[13] = fmaxf(mm[13], bfhi(ub.z) + bfhi(vb.z));
                mm[14] = fmaxf(mm[14], bflo(ub.w) + bflo(vb.w));
                mm[15] = fmaxf(mm[15], bfhi(ub.w) + bfhi(vb.w));
            }
#pragma unroll
            for (int j = 0; j < 16; ++j)
                sm[seg][cgi * 16 + j] = fmaxf(mm[j] + bv[j], 0.0f);
            __syncthreads();

            const int g = tid >> 5, l = tid & 31;
            if (fp32) {
                float* op = (float*)out_;
#pragma unroll
                for (int rr = 0; rr < 16; ++rr) {
                    int ol = g * 16 + rr;
                    int o  = third * 128 + ol;
                    op[((size_t)b * CO + o) * Nn + n0 + l] = sm[l][ol];
                }
            } else {
                __hip_bfloat16* op = (__hip_bfloat16*)out_;
#pragma unroll
                for (int rr = 0; rr < 16; ++rr) {
                    int ol = g * 16 + rr;
                    int o  = third * 128 + ol;
                    op[((size_t)b * CO + o) * Nn + n0 + l] = __float2bfloat16(sm[l][ol]);
                }
            }
            __syncthreads();
        }
    }
}

extern "C" void kernel_launch(void* const* d_in, const int* in_sizes, int n_in,
                              void* d_out, int out_size, void* d_ws, size_t ws_size,
                              hipStream_t stream) {
    const void* x  = d_in[0];
    const int*  ei = (const int*)d_in[1];
    const void* W  = d_in[2];
    const void* bs = d_in[3];
    void* out = d_out;

    char* ws = (char*)d_ws;
    short* A_Tb  = (short*)(ws + 1024);                    // 768*200*2
    short* xT    = (short*)(ws + (512u << 10));            // 8*3136*200*2
    short* T     = (short*)(ws + (11u << 20));             // 8*3136*768*2

    static int nblk = 0;
    if (nblk == 0) {
        int maxb = 0;
        hipOccupancyMaxActiveBlocksPerMultiprocessor(&maxb, fused_all, 256, 0);
        if (maxb < 1) maxb = 1;
        if (maxb > 3) maxb = 3;
        nblk = (maxb * 256) & ~7;          // multiple of 8
        if (nblk < 8) nblk = 8;
    }

    void* args[] = {(void*)&x, (void*)&ei, (void*)&W, (void*)&bs,
                    (void*)&out, (void*)&xT, (void*)&A_Tb, (void*)&T};
    hipLaunchCooperativeKernel((void*)fused_all, dim3(nblk), dim3(256),
                               args, 0, stream);
}

// Round 5
// 129.778 us; speedup vs baseline: 2.1393x; 2.1393x over previous
//
#include <hip/hip_runtime.h>
#include <hip/hip_bf16.h>

// B=8, C=192, N=3136, K=9, COUT=384.
// out[b,o,n] = relu( bias[o] + max_k( u[b,i1,o] + v[b,i0,o] ) )
//   u = (W1-W2)·xs,  v = W2·xs   (per-node GEMMs; 9x less compute than per-edge)
// 3-kernel pipeline (Round-4 fusion experiment showed all pipes idle -> latency-bound;
// separate launches beat persistent+grid.sync because fresh blocks arrive phase-staggered):
//   prep_fused: inline-detect dtypes + x->x_T[b][n][200] bf16 + W->A_Tb[j][200] bf16
//   gemm_mfma : T[b][n][768]; single-shot K=192; A-tile via linear global_load_lds DMA;
//               B-fragments DIRECT from global (A_Tb = 307KB, L2-hot) issued BEFORE the
//               staging barrier -> LDS 25.6KB -> 6 blocks/CU (was 3) for stall overlap
//   gather_max: QUARTER-split gather; byte-offsets precomputed in LDS; 16B loads
// ws: flags @0 | A_Tb @1KB (307KB) | x_T @512KB (10.0MB) | T @11MB (38.5MB) ~= 49.5MB

#define Bb   8
#define Cc   192
#define Nn   3136
#define Kk   9
#define CO   384
#define TWOC 384
#define JTOT 768
#define PADC 200   // row length in xT/A_Tb AND LDS (shorts): 400B rows

typedef short  short8 __attribute__((ext_vector_type(8)));
typedef float  f32x4  __attribute__((ext_vector_type(4)));

__device__ __forceinline__ float bf2f(unsigned int u16) {
    union { unsigned int i; float f; } c;
    c.i = u16 << 16;
    return c.f;
}
__device__ __forceinline__ float bflo(unsigned int u) {
    union { unsigned int i; float f; } c;
    c.i = u << 16;
    return c.f;
}
__device__ __forceinline__ float bfhi(unsigned int u) {
    union { unsigned int i; float f; } c;
    c.i = u & 0xffff0000u;
    return c.f;
}
__device__ __forceinline__ short f2bf(float f) {
    __hip_bfloat16 h = __float2bfloat16(f);
    short s; __builtin_memcpy(&s, &h, 2); return s;
}
// async 16B global -> LDS DMA; LDS dest = wave-uniform base + lane*16
__device__ __forceinline__ void gload16(const void* g, void* l) {
    __builtin_amdgcn_global_load_lds(
        (const __attribute__((address_space(1))) unsigned int*)g,
        (__attribute__((address_space(3))) unsigned int*)l, 16, 0, 0);
}

// ---------------- K1: fused detect + transpose_x + prep_AT ----------------
__global__ __launch_bounds__(256) void prep_fused(const void* __restrict__ x_,
                                                  const void* __restrict__ W_,
                                                  const int* __restrict__ ei,
                                                  short* __restrict__ xT,
                                                  short* __restrict__ A_Tb,
                                                  int* __restrict__ flags) {
    __shared__ float s[64][33];
    __shared__ int sflag;
    const int tid = threadIdx.x;
    const int bid = blockIdx.x;

    if (tid < 64) {
        unsigned int u = ((const unsigned short*)x_)[2 * tid];
        int bige = (((u >> 7) & 0xFFu) >= 0x88u);   // impossible for N(0,1) bf16
        unsigned long long bf = __ballot(bige);
        int f32 = (bf != 0ull) ? 1 : 0;
        if (tid == 0) sflag = f32;
        if (bid == 0) {
            int oddnz = (ei[2 * tid + 1] != 0);
            unsigned long long bo = __ballot(oddnz);
            if (tid == 0) {
                flags[0] = f32;                      // floats are fp32
                flags[1] = (bo == 0ull) ? 1 : 0;     // indices are int64
            }
        }
    }
    __syncthreads();
    const int fp32 = sflag;

    if (bid < 2352) {
        int b   = bid / 294;              // 294 = 6*49
        int rem = bid - b * 294;
        int ct  = rem / 49;
        int nt  = rem - ct * 49;
        const int n0 = nt * 64;
        const int c0 = ct * 32;
        const int cl   = tid >> 3;
        const int nseg = tid & 7;

        if (fp32) {
            const float* p = (const float*)x_ + ((size_t)b * Cc + c0 + cl) * Nn + n0 + nseg * 8;
            float4 v0 = *(const float4*)p;
            float4 v1 = *(const float4*)(p + 4);
            int nb = nseg * 8;
            s[nb + 0][cl] = v0.x;  s[nb + 1][cl] = v0.y;
            s[nb + 2][cl] = v0.z;  s[nb + 3][cl] = v0.w;
            s[nb + 4][cl] = v1.x;  s[nb + 5][cl] = v1.y;
            s[nb + 6][cl] = v1.z;  s[nb + 7][cl] = v1.w;
        } else {
            const unsigned short* p = (const unsigned short*)x_ + ((size_t)b * Cc + c0 + cl) * Nn + n0 + nseg * 8;
            ushort4 u0 = *(const ushort4*)p;
            ushort4 u1 = *(const ushort4*)(p + 4);
            int nb = nseg * 8;
            s[nb + 0][cl] = bf2f(u0.x);  s[nb + 1][cl] = bf2f(u0.y);
            s[nb + 2][cl] = bf2f(u0.z);  s[nb + 3][cl] = bf2f(u0.w);
            s[nb + 4][cl] = bf2f(u1.x);  s[nb + 5][cl] = bf2f(u1.y);
            s[nb + 6][cl] = bf2f(u1.z);  s[nb + 7][cl] = bf2f(u1.w);
        }
        __syncthreads();

        const int nl = tid >> 2;
        const int cs = tid & 3;
        short8 o;
#pragma unroll
        for (int i = 0; i < 8; ++i) o[i] = f2bf(s[nl][cs * 8 + i]);
        *(short8*)(xT + ((size_t)b * Nn + n0 + nl) * PADC + c0 + cs * 8) = o;
    } else {
        int t = (bid - 2352) * 256 + tid;        // 0..147455 exactly
        int j = t / Cc;
        int c = t - j * Cc;
        int row = (j < CO) ? j : (j - CO);
        float w1, w2;
        if (fp32) {
            const float* W = (const float*)W_;
            w1 = W[row * TWOC + c];  w2 = W[row * TWOC + Cc + c];
        } else {
            const unsigned short* W = (const unsigned short*)W_;
            w1 = bf2f(W[row * TWOC + c]);  w2 = bf2f(W[row * TWOC + Cc + c]);
        }
        A_Tb[(size_t)j * PADC + c] = f2bf((j < CO) ? (w1 - w2) : w2);
    }
}

// ---------------- K2: MFMA GEMM, single-shot K=192 ----------------
// A-tile: linear global_load_lds (global tile is byte-image of LDS tile, 25x1KB).
// B-fragments: direct global loads (A_Tb 307KB, L2-resident & hot from 4704 re-reads),
// issued BEFORE the staging __syncthreads so their latency hides under the vmcnt drain.
// LDS 25.6KB -> 6 blocks/CU: doubles cross-block latency overlap vs the 3-block version.
__global__ __launch_bounds__(256, 6) void gemm_mfma(const short* __restrict__ xT,
                                                    const short* __restrict__ A_Tb,
                                                    short* __restrict__ T) {
    __shared__ short Asl[64 * PADC];   // 25,600 B  [n][c]

    const int n0 = blockIdx.x * 64;
    const int j0 = blockIdx.y * 64;
    const int b  = blockIdx.z;
    const int tid  = threadIdx.x;
    const int w    = tid >> 6;
    const int lane = tid & 63;
    const int col  = lane & 15;
    const int quad = lane >> 4;

    // stage A-tile: pure linear copy, 25 x 1KB chunks
    {
        const short* gA = xT + ((size_t)b * Nn + n0) * PADC;
        for (int c = w; c < 25; c += 4) {
            gload16(gA + c * 512 + lane * 8, Asl + c * 512);
        }
    }

    // B-fragments direct from global, issued before the barrier (latency overlaps drain)
    short8 bfr[6];
    {
        const short* gB = A_Tb + (size_t)(j0 + w * 16 + col) * PADC + quad * 8;
#pragma unroll
        for (int kf = 0; kf < 6; ++kf) {
            bfr[kf] = *(const short8*)(gB + kf * 32);
        }
    }
    __syncthreads();

    f32x4 acc[4];
#pragma unroll
    for (int i = 0; i < 4; ++i) acc[i] = (f32x4)(0.0f);

#pragma unroll
    for (int kf = 0; kf < 6; ++kf) {
#pragma unroll
        for (int fm = 0; fm < 4; ++fm) {
            short8 a = *(const short8*)(Asl + (fm * 16 + col) * PADC + kf * 32 + quad * 8);
            acc[fm] = __builtin_amdgcn_mfma_f32_16x16x32_bf16(a, bfr[kf], acc[fm], 0, 0, 0);
        }
    }
    __syncthreads();   // all LDS reads done; reuse Asl as C-tile

    // epilogue: acc -> LDS [64n][72] -> full-line coalesced global stores
    short* Ct = Asl;
#pragma unroll
    for (int fm = 0; fm < 4; ++fm) {
#pragma unroll
        for (int r = 0; r < 4; ++r) {
            Ct[(fm * 16 + quad * 4 + r) * 72 + w * 16 + col] = f2bf(acc[fm][r]);
        }
    }
    __syncthreads();

    {
        const int row = tid >> 2;        // 0..63
        const int gq  = tid & 3;
#pragma unroll
        for (int i = 0; i < 2; ++i) {
            int g = gq + i * 4;
            *(short8*)(T + ((size_t)(b * Nn + n0 + row)) * JTOT + j0 + g * 8) =
                *(const short8*)(Ct + row * 72 + g * 8);
        }
    }
}

// ---------------- K3: gather + max + bias + relu (quarter-split for L2 residency) ----------------
// bid = b + 8*(tile + 98*quarter); working set per (b,quarter) = 2 x 0.6MB = 1.2MB << 4MB L2.
// Node indices pre-scaled to BYTE offsets (idx*JTOT*2) in LDS; 1 node x 8 ch per thread, 16B loads.
__global__ __launch_bounds__(384) void gather_max(const int* __restrict__ ei,
                                                  const short* __restrict__ T,
                                                  const void* __restrict__ bias_,
                                                  void* __restrict__ out_,
                                                  const int* __restrict__ flags) {
    __shared__ float sm[32][97];     // [node][local channel], pad 97
    __shared__ int soff0[32][Kk];    // byte offsets: idx0*JTOT*2
    __shared__ int soff1[32][Kk];    // byte offsets: idx1*JTOT*2

    const int fp32 = flags[0];
    const int is64 = flags[1];
    const int bid  = blockIdx.x;
    const int b    = bid & 7;
    const int rest = bid >> 3;        // 0..391
    const int quarter = rest / 98;    // 0..3
    const int n0   = (rest % 98) * 32;
    const int tid  = threadIdx.x;

    for (int s = tid; s < 32 * 2 * Kk; s += 384) {
        int ln = s / (2 * Kk);
        int slot = s - ln * (2 * Kk);
        int n = n0 + ln;
        size_t pos; int* dstp;
        if (slot < Kk) { pos = ((size_t)b * Nn + n) * Kk + slot;               dstp = &soff0[ln][slot]; }
        else           { pos = ((size_t)(Bb + b) * Nn + n) * Kk + (slot - Kk); dstp = &soff1[ln][slot - Kk]; }
        int v = is64 ? ei[2 * pos] : ei[pos];
        v = (v < 0) ? 0 : (v >= Nn ? Nn - 1 : v);
        *dstp = v * (JTOT * 2);
    }
    __syncthreads();

    // phase 1: thread (cg, seg): 8 channels (16B loads), 1 node
    const int cg  = tid % 12;               // channel group of 8 within quarter
    const int seg = tid / 12;               // node 0..31
    const int och = quarter * 96 + cg * 8;
    const char* Tb = (const char*)T + (size_t)b * Nn * JTOT * 2;
    const char* Tu = Tb + (size_t)och * 2;          // u-part (first 384 channels)
    const char* Tv = Tb + (size_t)(CO + och) * 2;   // v-part

    float bv[8];
    if (fp32) {
        const float* bp = (const float*)bias_ + och;
#pragma unroll
        for (int j = 0; j < 8; ++j) bv[j] = bp[j];
    } else {
        const unsigned short* bp = (const unsigned short*)bias_ + och;
#pragma unroll
        for (int j = 0; j < 8; ++j) bv[j] = bf2f(bp[j]);
    }

    float m0 = -INFINITY, m1 = -INFINITY, m2 = -INFINITY, m3 = -INFINITY;
    float m4 = -INFINITY, m5 = -INFINITY, m6 = -INFINITY, m7 = -INFINITY;
#pragma unroll
    for (int k = 0; k < Kk; ++k) {
        const int o1 = soff1[seg][k];
        const int o0 = soff0[seg][k];
        uint4 uu = *(const uint4*)(Tu + o1);
        uint4 vv = *(const uint4*)(Tv + o0);
        m0 = fmaxf(m0, bflo(uu.x) + bflo(vv.x));
        m1 = fmaxf(m1, bfhi(uu.x) + bfhi(vv.x));
        m2 = fmaxf(m2, bflo(uu.y) + bflo(vv.y));
        m3 = fmaxf(m3, bfhi(uu.y) + bfhi(vv.y));
        m4 = fmaxf(m4, bflo(uu.z) + bflo(vv.z));
        m5 = fmaxf(m5, bfhi(uu.z) + bfhi(vv.z));
        m6 = fmaxf(m6, bflo(uu.w) + bflo(vv.w));
        m7 = fmaxf(m7, bfhi(uu.w) + bfhi(vv.w));
    }
    sm[seg][cg * 8 + 0] = fmaxf(m0 + bv[0], 0.0f);
    sm[seg][cg * 8 + 1] = fmaxf(m1 + bv[1], 0.0f);
    sm[seg][cg * 8 + 2] = fmaxf(m2 + bv[2], 0.0f);
    sm[seg][cg * 8 + 3] = fmaxf(m3 + bv[3], 0.0f);
    sm[seg][cg * 8 + 4] = fmaxf(m4 + bv[4], 0.0f);
    sm[seg][cg * 8 + 5] = fmaxf(m5 + bv[5], 0.0f);
    sm[seg][cg * 8 + 6] = fmaxf(m6 + bv[6], 0.0f);
    sm[seg][cg * 8 + 7] = fmaxf(m7 + bv[7], 0.0f);
    __syncthreads();

    // phase 2: transposed coalesced writes; 12 groups x 8 rows x 32 lanes
    const int g = tid >> 5, l = tid & 31;
    if (fp32) {
        float* op = (float*)out_;
#pragma unroll
        for (int rr = 0; rr < 8; ++rr) {
            int ol = g * 8 + rr;
            int o  = quarter * 96 + ol;
            op[((size_t)b * CO + o) * Nn + n0 + l] = sm[l][ol];
        }
    } else {
        __hip_bfloat16* op = (__hip_bfloat16*)out_;
#pragma unroll
        for (int rr = 0; rr < 8; ++rr) {
            int ol = g * 8 + rr;
            int o  = quarter * 96 + ol;
            op[((size_t)b * CO + o) * Nn + n0 + l] = __float2bfloat16(sm[l][ol]);
        }
    }
}

extern "C" void kernel_launch(void* const* d_in, const int* in_sizes, int n_in,
                              void* d_out, int out_size, void* d_ws, size_t ws_size,
                              hipStream_t stream) {
    const void* x  = d_in[0];
    const int*  ei = (const int*)d_in[1];
    const void* W  = d_in[2];
    const void* bs = d_in[3];

    char* ws = (char*)d_ws;
    int*   flags = (int*)ws;                               // 64 B
    short* A_Tb  = (short*)(ws + 1024);                    // 768*200*2 = 307,200 B
    short* xT    = (short*)(ws + (512u << 10));            // 8*3136*200*2 = 10,035,200 B
    short* T     = (short*)(ws + (11u << 20));             // 8*3136*768*2 = 38,535,168 B

    prep_fused<<<2352 + 576, 256, 0, stream>>>(x, W, ei, xT, A_Tb, flags);

    dim3 g1(Nn / 64, JTOT / 64, Bb);   // (49, 12, 8) = 4704 blocks
    gemm_mfma<<<g1, 256, 0, stream>>>(xT, A_Tb, T);

    gather_max<<<Bb * 4 * (Nn / 32), 384, 0, stream>>>(ei, T, bs, d_out, flags);
}